// Round 23
// baseline (408.454 us; speedup 1.0000x reference)
//
#include <hip/hip_runtime.h>

#define N_SUB 200000
#define N_GR  4096
#define DIM   256
#define HID   512
#define TCLS  10
#define MROWS 64
#define RCAP  16384
#define RMARG 1e-3f
#define NREP  128            // S/Se replica count (atomic de-contention)

typedef __attribute__((ext_vector_type(8))) short short8;
typedef __attribute__((ext_vector_type(4))) float f32x4;

__device__ __forceinline__ short bf16_rne(float x){
  unsigned u = __builtin_bit_cast(unsigned, x);
  unsigned r = (u + 0x7FFFu + ((u >> 16) & 1u)) >> 16;
  return (short)r;
}
__device__ __forceinline__ float bf16_to_f(short h){
  unsigned u = ((unsigned)(unsigned short)h) << 16;
  return __builtin_bit_cast(float, u);
}
__device__ __forceinline__ float wave_reduce(float v){
  #pragma unroll
  for (int d = 1; d < 64; d <<= 1) v += __shfl_xor(v, d, 64);
  return v;
}
// swizzled fragment-major A granule index (16B granules); ks 0..7, mt 0..3 (r15-proven)
__device__ __forceinline__ int a_gran(int mt, int mrow, int ks, int kgrp){
  return (((((mt*8 + ks)*4 + kgrp)*2 + (mrow>>3)) << 3)
          | ((mrow & 7) ^ ((ks & 3) << 1) ^ (kgrp & 1)));
}

// ---------------- bconv + fused init ----------------
__global__ __launch_bounds__(256) void bconv_kernel(const float* __restrict__ W1,
                                                    short* __restrict__ bth,
                                                    short* __restrict__ btl,
                                                    int* cnt_all, float* S32, float* Se32,
                                                    float* S, float* Se,
                                                    int* counters, float* loss_p, int* rcnt){
  const int i = blockIdx.x*256 + threadIdx.x;
  if (i < N_GR) cnt_all[i] = 0;
  if (i < NREP*DIM){ S32[i] = 0.f; Se32[i] = 0.f; }
  if (i < DIM){ S[i] = 0.f; Se[i] = 0.f; }
  if (i < 64) loss_p[i] = 0.f;
  if (i < 2) counters[i] = 0;
  if (i == 0) rcnt[0] = 0;
  const int k = i >> 9;
  const int j = i & 511;
  const float x = W1[i];
  const short h = bf16_rne(x);
  const short l = bf16_rne(x - bf16_to_f(h));
  const int nt = j >> 4, mrow = j & 15;
  const int ksg = k >> 5, kgrp = (k >> 3) & 3, kk = k & 7;
  const int lane = kgrp*16 + mrow;
  const size_t dst = (((size_t)(nt*8 + ksg)*64 + lane) << 3) + kk;
  bth[dst] = h;
  btl[dst] = l;
}

// ---------------- kernel A: 2-tile pipelined nt-split 16-wave ----------------
// 1024 thr = 16 waves; block does 2 tiles of 64 rows; BOTH tiles' global loads
// issued up front (T14 issue-early) so tile-2 HBM latency hides under tile-1 MFMA.
__global__ __launch_bounds__(1024) void mask_gemm(
    const float* __restrict__ hsub, const short* __restrict__ bth,
    const short* __restrict__ btl, const float* __restrict__ b1,
    const float* __restrict__ W2, const float* __restrict__ b2,
    const int* __restrict__ s2g, float* __restrict__ mask_out,
    int* __restrict__ cnt_all, int* __restrict__ rlist, int* __restrict__ rcnt)
{
  __shared__ short a_hi[16384];     // 32 KB swizzled fragment-major (64 rows x 256 k)
  __shared__ short a_lo[16384];     // 32 KB
  __shared__ float sred[1024];      // 4 KB  -> 68 KB total
  const int tid = threadIdx.x;
  const int lane = tid & 63;
  const int c = tid >> 6;           // wave 0..15
  const int mrow = lane & 15;
  const int kgrp = lane >> 4;
  const int brow1 = blockIdx.x*(2*MROWS);
  const int brow2 = brow1 + MROWS;

  f32x4 acc[4][2];

#define CONVERT(G)                                                            \
  { _Pragma("unroll")                                                         \
    for (int i = 0; i < 4; ++i){                                              \
      const int idx = i*1024 + tid;                                           \
      const int rr = idx >> 6;                                                \
      const int ch = idx & 63;                                                \
      const float4 v = G[i];                                                  \
      const short h0=bf16_rne(v.x), h1=bf16_rne(v.y), h2=bf16_rne(v.z), h3=bf16_rne(v.w); \
      const short l0=bf16_rne(v.x-bf16_to_f(h0)), l1=bf16_rne(v.y-bf16_to_f(h1)); \
      const short l2=bf16_rne(v.z-bf16_to_f(h2)), l3=bf16_rne(v.w-bf16_to_f(h3)); \
      const int so = a_gran(rr>>4, rr&15, ch>>3, (ch>>1)&3)*8 + (ch&1)*4;     \
      *reinterpret_cast<short4*>(&a_hi[so]) = make_short4(h0,h1,h2,h3);       \
      *reinterpret_cast<short4*>(&a_lo[so]) = make_short4(l0,l1,l2,l3);       \
    } }

#define KSLOOP                                                                \
  { short8 Ah[4], Al[4];                                                      \
    _Pragma("unroll")                                                         \
    for (int ks = 0; ks < 8; ++ks){                                           \
      _Pragma("unroll")                                                       \
      for (int m = 0; m < 4; ++m){                                            \
        const int so = a_gran(m, mrow, ks, kgrp)*8;                           \
        Ah[m] = *reinterpret_cast<const short8*>(&a_hi[so]);                  \
        Al[m] = *reinterpret_cast<const short8*>(&a_lo[so]);                  \
      }                                                                       \
      _Pragma("unroll")                                                       \
      for (int nt = 0; nt < 2; ++nt){                                         \
        const int ntg = c*2 + nt;                                             \
        const size_t bo = (((size_t)(ntg*8 + ks)*64 + lane) << 3);            \
        const short8 Bh = *reinterpret_cast<const short8*>(bth + bo);         \
        const short8 Bl = *reinterpret_cast<const short8*>(btl + bo);         \
        _Pragma("unroll")                                                     \
        for (int m = 0; m < 4; ++m){                                          \
          acc[m][nt] = __builtin_amdgcn_mfma_f32_16x16x32_bf16(Ah[m], Bh, acc[m][nt], 0,0,0); \
          acc[m][nt] = __builtin_amdgcn_mfma_f32_16x16x32_bf16(Ah[m], Bl, acc[m][nt], 0,0,0); \
          acc[m][nt] = __builtin_amdgcn_mfma_f32_16x16x32_bf16(Al[m], Bh, acc[m][nt], 0,0,0); \
        } } } }

#define EPILOGUE(BROW)                                                        \
  { float w2v[2], b1v[2];                                                     \
    _Pragma("unroll")                                                         \
    for (int nt=0; nt<2; ++nt){                                               \
      const int n = c*32 + nt*16 + mrow;                                      \
      w2v[nt] = W2[n]; b1v[nt] = b1[n];                                       \
    }                                                                         \
    _Pragma("unroll")                                                         \
    for (int mt=0; mt<4; ++mt){                                               \
      _Pragma("unroll")                                                       \
      for (int r=0; r<4; ++r){                                                \
        float s = 0.f;                                                        \
        _Pragma("unroll")                                                     \
        for (int nt=0; nt<2; ++nt)                                            \
          s += fmaxf(acc[mt][nt][r] + b1v[nt], 0.f) * w2v[nt];                \
        s += __shfl_xor(s, 1, 64);                                            \
        s += __shfl_xor(s, 2, 64);                                            \
        s += __shfl_xor(s, 4, 64);                                            \
        s += __shfl_xor(s, 8, 64);                                            \
        if (mrow == 0)                                                        \
          sred[c*64 + mt*16 + kgrp*4 + r] = s;                                \
      } }                                                                     \
    __syncthreads();                                                          \
    if (tid < MROWS){                                                         \
      const int rr = (BROW) + tid;                                            \
      if (rr < N_SUB){                                                        \
        float tot = b2[0];                                                    \
        _Pragma("unroll")                                                     \
        for (int w = 0; w < 16; ++w) tot += sred[w*64 + tid];                 \
        const float m = 1.f / (1.f + expf(-tot));                             \
        mask_out[rr] = m;                                                     \
        atomicAdd(&cnt_all[s2g[rr]], 1);                                      \
        if (fabsf(m - 0.4f) < RMARG || fabsf(m - 0.3f) < RMARG){              \
          const int p = atomicAdd(rcnt, 1);                                   \
          if (p < RCAP) rlist[p] = rr;                                        \
        }                                                                     \
      } } }

  // ---- issue BOTH tiles' global loads up front ----
  float4 g1[4], g2[4];
  #pragma unroll
  for (int i = 0; i < 4; ++i){
    const int idx = i*1024 + tid;
    g1[i] = *reinterpret_cast<const float4*>(hsub + (size_t)(brow1 + (idx>>6))*DIM + (idx&63)*4);
  }
  #pragma unroll
  for (int i = 0; i < 4; ++i){
    const int idx = i*1024 + tid;
    const int rg = min(brow2 + (idx>>6), N_SUB-1);
    g2[i] = *reinterpret_cast<const float4*>(hsub + (size_t)rg*DIM + (idx&63)*4);
  }

  // ---- tile 1 ----
  #pragma unroll
  for (int mt=0; mt<4; ++mt)
    #pragma unroll
    for (int nt=0; nt<2; ++nt) acc[mt][nt] = (f32x4){0.f,0.f,0.f,0.f};
  CONVERT(g1);
  __syncthreads();
  KSLOOP;
  EPILOGUE(brow1);
  __syncthreads();     // sred reads done + LDS safe to overwrite

  // ---- tile 2 (skipped entirely by the final half-block) ----
  if (brow2 < N_SUB){
    #pragma unroll
    for (int mt=0; mt<4; ++mt)
      #pragma unroll
      for (int nt=0; nt<2; ++nt) acc[mt][nt] = (f32x4){0.f,0.f,0.f,0.f};
    CONVERT(g2);
    __syncthreads();
    KSLOOP;
    EPILOGUE(brow2);
  }
#undef CONVERT
#undef KSLOOP
#undef EPILOGUE
}

// ---------------- refine: exact fp32 logit, MLP-parallel ----------------
__global__ __launch_bounds__(512) void refine_kernel(
    const float* __restrict__ hsub, const float* __restrict__ W1,
    const float* __restrict__ b1, const float* __restrict__ W2,
    const float* __restrict__ b2, const int* __restrict__ rlist,
    const int* __restrict__ rcnt, float* __restrict__ mask_out)
{
  __shared__ float arow[256];
  __shared__ float red[512];
  const int n = min(rcnt[0], RCAP);
  const int t = threadIdx.x;            // j = t, 0..511
  for (int it = blockIdx.x; it < n; it += gridDim.x){
    const int row = rlist[it];
    if (t < 256) arow[t] = hsub[(size_t)row*DIM + t];
    __syncthreads();
    float y0 = b1[t], y1 = 0.f, y2 = 0.f, y3 = 0.f;
    #pragma unroll 8
    for (int k = 0; k < 64; ++k){
      y0 = fmaf(arow[k],     W1[(size_t)k*512 + t],         y0);
      y1 = fmaf(arow[k+64],  W1[(size_t)(k+64)*512 + t],    y1);
      y2 = fmaf(arow[k+128], W1[(size_t)(k+128)*512 + t],   y2);
      y3 = fmaf(arow[k+192], W1[(size_t)(k+192)*512 + t],   y3);
    }
    const float y = (y0 + y1) + (y2 + y3);
    red[t] = fmaxf(y, 0.f) * W2[t];
    __syncthreads();
    #pragma unroll
    for (int off = 256; off > 0; off >>= 1){
      if (t < off) red[t] += red[t+off];
      __syncthreads();
    }
    if (t == 0) mask_out[row] = 1.f / (1.f + expf(-(red[0] + b2[0])));
    __syncthreads();
  }
}

// ---------------- CSR build: scan + fill ----------------
__global__ __launch_bounds__(1024) void scan_kernel(const int* __restrict__ cnt,
                                                    int* __restrict__ offs,
                                                    int* __restrict__ cursor){
  __shared__ int buf[1024];
  const int t = threadIdx.x;
  const int c0 = cnt[t*4], c1 = cnt[t*4+1], c2 = cnt[t*4+2], c3 = cnt[t*4+3];
  const int s = c0+c1+c2+c3;
  buf[t] = s; __syncthreads();
  for (int d = 1; d < 1024; d <<= 1){
    int v = (t >= d) ? buf[t-d] : 0;
    __syncthreads();
    buf[t] += v;
    __syncthreads();
  }
  const int excl = buf[t] - s;
  const int o0 = excl, o1 = excl+c0, o2 = o1+c1, o3 = o2+c2;
  offs[t*4]=o0; offs[t*4+1]=o1; offs[t*4+2]=o2; offs[t*4+3]=o3;
  cursor[t*4]=o0; cursor[t*4+1]=o1; cursor[t*4+2]=o2; cursor[t*4+3]=o3;
  if (t == 1023) offs[4096] = buf[1023];
}

__global__ void fill_kernel(const int* __restrict__ s2g, int* __restrict__ cursor,
                            int* __restrict__ list){
  const int i = blockIdx.x*blockDim.x + threadIdx.x;
  if (i < N_SUB){
    const int g = s2g[i];
    const int p = atomicAdd(&cursor[g], 1);
    list[p] = i;
  }
}

// ---------------- kernel C: per-graph masked means (replica-spread atomics) ----------------
__global__ __launch_bounds__(256) void graph_means(
    const float* __restrict__ hsub, const float* __restrict__ mask,
    const int* __restrict__ list, const int* __restrict__ offs,
    const float* __restrict__ hgraph, const float* __restrict__ Wc,
    const float* __restrict__ bc, unsigned short* __restrict__ hatAb,
    float* __restrict__ S32, float* __restrict__ Se32,
    int* __restrict__ nzflags, int* __restrict__ counters,
    float* __restrict__ out)
{
  __shared__ int   sidx[256];
  __shared__ unsigned char sflag[256];
  __shared__ float wr4[4][4];
  __shared__ float wrc[TCLS][4];
  const int g = blockIdx.x;
  const int t = threadIdx.x;
  const int w = t >> 6, lane = t & 63;
  const int start = offs[g], end = offs[g+1];
  const int cnt = end - start;
  float sv = 0.f, sev = 0.f;
  int cv = 0, ce = 0;
  for (int base = 0; base < cnt; base += 256){
    const int nb = min(256, cnt - base);
    __syncthreads();
    if (t < nb){
      const int i = list[start + base + t];
      sidx[t] = i;
      const float m = mask[i];
      sflag[t] = (m > 0.4f) ? 1 : ((m <= 0.3f) ? 2 : 0);
    }
    __syncthreads();
    for (int p = 0; p < nb; p += 4){
      const int lim = nb - p;
      const int i0 = sidx[p];
      const int i1 = (lim > 1) ? sidx[p+1] : i0;
      const int i2 = (lim > 2) ? sidx[p+2] : i0;
      const int i3 = (lim > 3) ? sidx[p+3] : i0;
      const int f0 = sflag[p];
      const int f1 = (lim > 1) ? sflag[p+1] : 0;
      const int f2 = (lim > 2) ? sflag[p+2] : 0;
      const int f3 = (lim > 3) ? sflag[p+3] : 0;
      const float v0 = hsub[(size_t)i0*DIM + t];
      const float v1 = hsub[(size_t)i1*DIM + t];
      const float v2 = hsub[(size_t)i2*DIM + t];
      const float v3 = hsub[(size_t)i3*DIM + t];
      if (f0==1){ sv+=v0; cv++; } else if (f0==2){ sev+=v0; ce++; }
      if (f1==1){ sv+=v1; cv++; } else if (f1==2){ sev+=v1; ce++; }
      if (f2==1){ sv+=v2; cv++; } else if (f2==2){ sev+=v2; ce++; }
      if (f3==1){ sv+=v3; cv++; } else if (f3==2){ sev+=v3; ce++; }
    }
  }
  __syncthreads();
  const float aligned = sv  / fmaxf((float)cv, 1.f);
  const float envv    = sev / fmaxf((float)ce, 1.f);
  float r0 = wave_reduce(aligned*aligned);
  float r1 = wave_reduce(envv*envv);
  float r2 = wave_reduce(aligned != 0.f ? 1.f : 0.f);
  float r3 = wave_reduce(envv    != 0.f ? 1.f : 0.f);
  if (lane == 0){ wr4[w][0]=r0; wr4[w][1]=r1; wr4[w][2]=r2; wr4[w][3]=r3; }
  __syncthreads();
  const float an2  = wr4[0][0]+wr4[1][0]+wr4[2][0]+wr4[3][0];
  const float en2  = wr4[0][1]+wr4[1][1]+wr4[2][1]+wr4[3][1];
  const float nzpf = wr4[0][2]+wr4[1][2]+wr4[2][2]+wr4[3][2];
  const float nzef = wr4[0][3]+wr4[1][3]+wr4[2][3]+wr4[3][3];
  const bool nzp = nzpf > 0.f, nze = nzef > 0.f;
  const float an = fmaxf(sqrtf(an2), 1e-8f);
  const float en = fmaxf(sqrtf(en2), 1e-8f);
  const float ha = aligned / an;
  hatAb[(size_t)g*DIM + t] = (unsigned short)bf16_rne(ha);
  atomicAdd(&S32[((g & (NREP-1)) << 8) + t], ha);
  if (nze) atomicAdd(&Se32[((g & (NREP-1)) << 8) + t], envv / en);
  if (t == 0){
    nzflags[g] = nzp ? 1 : 0;
    if (nzp) atomicAdd(&counters[0], 1);
    if (nze) atomicAdd(&counters[1], 1);
  }
  const float hg = hgraph[(size_t)g*DIM + t];
  #pragma unroll
  for (int c = 0; c < TCLS; ++c){
    float part = hg*Wc[t*TCLS+c] + aligned*Wc[(DIM+t)*TCLS+c];
    part = wave_reduce(part);
    if (lane == 0) wrc[c][w] = part;
  }
  __syncthreads();
  if (t < TCLS)
    out[g*TCLS + t] = wrc[t][0]+wrc[t][1]+wrc[t][2]+wrc[t][3] + bc[t];
}

// ---------------- combine: fold S/Se replicas (16 blocks x 8 reps + atomic merge) ----------------
__global__ __launch_bounds__(256) void combine_kernel(const float* __restrict__ S32,
                                                      const float* __restrict__ Se32,
                                                      float* __restrict__ S,
                                                      float* __restrict__ Se){
  const int b = blockIdx.x;       // 0..15
  const int t = threadIdx.x;
  float s = 0.f, se = 0.f;
  #pragma unroll
  for (int r = 0; r < 8; ++r){
    s  += S32[(b*8 + r)*DIM + t];
    se += Se32[(b*8 + r)*DIM + t];
  }
  atomicAdd(&S[t], s);
  atomicAdd(&Se[t], se);
}

// ---------------- kernel D: contrastive loss via rank-1 identity ----------------
__global__ __launch_bounds__(256) void loss_kernel(
    const unsigned short* __restrict__ hatAb, const float* __restrict__ S,
    const float* __restrict__ Se, const int* __restrict__ nzflags,
    const int* __restrict__ counters, float* __restrict__ loss_p)
{
  __shared__ float wr[4][2];
  const int g = blockIdx.x, t = threadIdx.x;
  const int w = t >> 6, lane = t & 63;
  const float ha = bf16_to_f((short)hatAb[(size_t)g*DIM + t]);
  float p0 = wave_reduce(ha*S[t]);
  float p1 = wave_reduce(ha*Se[t]);
  if (lane == 0){ wr[w][0] = p0; wr[w][1] = p1; }
  __syncthreads();
  if (t == 0){
    const float dS  = wr[0][0]+wr[1][0]+wr[2][0]+wr[3][0];
    const float dSe = wr[0][1]+wr[1][1]+wr[2][1]+wr[3][1];
    const int nzp_cnt = counters[0];
    const int nenv = counters[1];
    const float pos_num = fmaxf((float)(nzp_cnt - 1), 1.f);
    const float positive = (4096.f - dS) / pos_num;
    const float negative = ((float)nenv - dSe) / fmaxf((float)nenv, 1.f);
    float contrib = fmaxf(positive - negative + 1.f, 0.f);
    contrib *= (nzflags[g] ? 1.f : 0.f) * ((nenv > 0) ? 1.f : 0.f);
    atomicAdd(&loss_p[g & 63], contrib * (1.f/4096.f));
  }
}

// ---------------- final: fold loss partials ----------------
__global__ void final_loss(const float* __restrict__ loss_p, float* __restrict__ loss){
  const int t = threadIdx.x;    // 64 threads
  float v = loss_p[t];
  v = wave_reduce(v);
  if (t == 0) loss[0] = v;
}

// ---------------- launch ----------------
extern "C" void kernel_launch(void* const* d_in, const int* in_sizes, int n_in,
                              void* d_out, int out_size, void* d_ws, size_t ws_size,
                              hipStream_t stream) {
  const float* h_graph = (const float*)d_in[0];
  const float* h_sub   = (const float*)d_in[1];
  const float* W1      = (const float*)d_in[2];
  const float* b1      = (const float*)d_in[3];
  const float* W2      = (const float*)d_in[4];
  const float* b2      = (const float*)d_in[5];
  const float* Wc      = (const float*)d_in[6];
  const float* bc      = (const float*)d_in[7];
  const int*   s2g     = (const int*)d_in[8];

  float* out  = (float*)d_out;          // [4096,10]
  float* loss = out + N_GR*TCLS;        // scalar
  float* mask = loss + 1;               // [200000]

  // workspace layout — ~3.9 MB (proven-safe envelope 5.06 MB)
  char* ws = (char*)d_ws;
  short* bth    = (short*)ws;                          // 256 KB
  short* btl    = bth + HID*DIM;                       // 256 KB
  unsigned short* hatAb = (unsigned short*)(btl + HID*DIM);  // 2 MB
  int* cnt_all  = (int*)(hatAb + (size_t)N_GR*DIM);    // 4096
  int* offs     = cnt_all + N_GR;                      // 4097
  int* cursor   = offs + N_GR + 1;                     // 4096
  int* list     = cursor + N_GR;                       // 200000
  int* nzflags  = list + N_SUB;                        // 4096
  int* counters = nzflags + N_GR;                      // 2
  int* rcnt     = counters + 2;                        // 1
  int* rlist    = rcnt + 1;                            // 16384
  float* S      = (float*)(rlist + RCAP);              // 256
  float* Se     = S + DIM;                             // 256
  float* S32    = Se + DIM;                            // 128*256 (128 KB)
  float* Se32   = S32 + NREP*DIM;                      // 128*256 (128 KB)
  float* loss_p = Se32 + NREP*DIM;                     // 64

  hipLaunchKernelGGL(bconv_kernel, dim3(HID*DIM/256), dim3(256), 0, stream,
                     W1, bth, btl, cnt_all, S32, Se32, S, Se, counters, loss_p, rcnt);
  hipLaunchKernelGGL(mask_gemm, dim3((N_SUB + 2*MROWS - 1)/(2*MROWS)), dim3(1024), 0, stream,
                     h_sub, bth, btl, b1, W2, b2, s2g, mask, cnt_all, rlist, rcnt);
  hipLaunchKernelGGL(refine_kernel, dim3(384), dim3(512), 0, stream,
                     h_sub, W1, b1, W2, b2, rlist, rcnt, mask);
  hipLaunchKernelGGL(scan_kernel, dim3(1), dim3(1024), 0, stream,
                     cnt_all, offs, cursor);
  hipLaunchKernelGGL(fill_kernel, dim3((N_SUB+255)/256), dim3(256), 0, stream,
                     s2g, cursor, list);
  hipLaunchKernelGGL(graph_means, dim3(N_GR), dim3(256), 0, stream,
                     h_sub, mask, list, offs, h_graph, Wc, bc,
                     hatAb, S32, Se32, nzflags, counters, out);
  hipLaunchKernelGGL(combine_kernel, dim3(16), dim3(256), 0, stream,
                     S32, Se32, S, Se);
  hipLaunchKernelGGL(loss_kernel, dim3(N_GR), dim3(256), 0, stream,
                     hatAb, S, Se, nzflags, counters, loss_p);
  hipLaunchKernelGGL(final_loss, dim3(1), dim3(64), 0, stream,
                     loss_p, loss);
}

// Round 24
// 397.543 us; speedup vs baseline: 1.0274x; 1.0274x over previous
//
#include <hip/hip_runtime.h>

#define N_SUB 200000
#define N_GR  4096
#define DIM   256
#define HID   512
#define TCLS  10
#define MROWS 32             // 6250 * 32 = 200000 exactly; acc[2][4]=32 AGPR -> no spill
#define RCAP  16384
#define RMARG 1e-3f
#define NREP  32             // S/Se replica count (r20-measured best tail)

typedef __attribute__((ext_vector_type(8))) short short8;
typedef __attribute__((ext_vector_type(4))) float f32x4;

__device__ __forceinline__ short bf16_rne(float x){
  unsigned u = __builtin_bit_cast(unsigned, x);
  unsigned r = (u + 0x7FFFu + ((u >> 16) & 1u)) >> 16;
  return (short)r;
}
__device__ __forceinline__ float bf16_to_f(short h){
  unsigned u = ((unsigned)(unsigned short)h) << 16;
  return __builtin_bit_cast(float, u);
}
__device__ __forceinline__ float wave_reduce(float v){
  #pragma unroll
  for (int d = 1; d < 64; d <<= 1) v += __shfl_xor(v, d, 64);
  return v;
}
// swizzled fragment-major A granule index (16B granules); ks 0..7, mt 0..1 (r21-proven)
__device__ __forceinline__ int a_gran(int mt, int mrow, int ks, int kgrp){
  return (((((mt*8 + ks)*4 + kgrp)*2 + (mrow>>3)) << 3)
          | ((mrow & 7) ^ ((ks & 3) << 1) ^ (kgrp & 1)));
}

// ---------------- bconv + fused init ----------------
__global__ __launch_bounds__(256) void bconv_kernel(const float* __restrict__ W1,
                                                    short* __restrict__ bth,
                                                    short* __restrict__ btl,
                                                    int* cnt_all, float* S32, float* Se32,
                                                    float* S, float* Se,
                                                    int* counters, float* loss_p, int* rcnt){
  const int i = blockIdx.x*256 + threadIdx.x;
  if (i < N_GR) cnt_all[i] = 0;
  if (i < NREP*DIM){ S32[i] = 0.f; Se32[i] = 0.f; }
  if (i < DIM){ S[i] = 0.f; Se[i] = 0.f; }
  if (i < 64) loss_p[i] = 0.f;
  if (i < 2) counters[i] = 0;
  if (i == 0) rcnt[0] = 0;
  const int k = i >> 9;
  const int j = i & 511;
  const float x = W1[i];
  const short h = bf16_rne(x);
  const short l = bf16_rne(x - bf16_to_f(h));
  const int nt = j >> 4, mrow = j & 15;
  const int ksg = k >> 5, kgrp = (k >> 3) & 3, kk = k & 7;
  const int lane = kgrp*16 + mrow;
  const size_t dst = (((size_t)(nt*8 + ksg)*64 + lane) << 3) + kk;
  bth[dst] = h;
  btl[dst] = l;
}

// ---------------- kernel A: 32 rows/block, acc[2][4], spill-free 2 blocks/CU (r21 best) ----------------
__global__ __launch_bounds__(512, 4) void mask_gemm(
    const float* __restrict__ hsub, const short* __restrict__ bth,
    const short* __restrict__ btl, const float* __restrict__ b1,
    const float* __restrict__ W2, const float* __restrict__ b2,
    const int* __restrict__ s2g, float* __restrict__ mask_out,
    int* __restrict__ cnt_all, int* __restrict__ rlist, int* __restrict__ rcnt)
{
  __shared__ short a_hi[8192];      // 16 KB swizzled fragment-major (32 rows x 256 k)
  __shared__ short a_lo[8192];      // 16 KB
  __shared__ float sred[256];       // 1 KB  -> 33 KB total
  const int tid = threadIdx.x;
  const int lane = tid & 63;
  const int q = tid >> 6;
  const int mrow = lane & 15;
  const int kgrp = lane >> 4;
  const int brow = blockIdx.x*MROWS;

  f32x4 acc[2][4];
  #pragma unroll
  for (int mt=0; mt<2; ++mt)
    #pragma unroll
    for (int nt=0; nt<4; ++nt) acc[mt][nt] = (f32x4){0.f,0.f,0.f,0.f};

  // ---- stage: 4 hoisted float4 loads per thread (32 rows x 64 chunks) ----
  const float* __restrict__ gbase = hsub + (size_t)brow*DIM;
  {
    float4 g[4];
    #pragma unroll
    for (int i = 0; i < 4; ++i){
      const int idx = i*512 + tid;               // float4 chunk 0..2047
      g[i] = *reinterpret_cast<const float4*>(gbase + (size_t)idx*4);
    }
    #pragma unroll
    for (int i = 0; i < 4; ++i){
      const int idx = i*512 + tid;
      const int rr = idx >> 6;                   // row 0..31
      const int ch = idx & 63;                   // full-K chunk 0..63
      const float4 v = g[i];
      const short h0=bf16_rne(v.x), h1=bf16_rne(v.y), h2=bf16_rne(v.z), h3=bf16_rne(v.w);
      const short l0=bf16_rne(v.x-bf16_to_f(h0)), l1=bf16_rne(v.y-bf16_to_f(h1));
      const short l2=bf16_rne(v.z-bf16_to_f(h2)), l3=bf16_rne(v.w-bf16_to_f(h3));
      const int so = a_gran(rr>>4, rr&15, ch>>3, (ch>>1)&3)*8 + (ch&1)*4;
      *reinterpret_cast<short4*>(&a_hi[so]) = make_short4(h0,h1,h2,h3);
      *reinterpret_cast<short4*>(&a_lo[so]) = make_short4(l0,l1,l2,l3);
    }
  }
  __syncthreads();

  short8 Ah[2], Al[2];
  #pragma unroll
  for (int ks = 0; ks < 8; ++ks){
    #pragma unroll
    for (int m = 0; m < 2; ++m){
      const int so = a_gran(m, mrow, ks, kgrp)*8;
      Ah[m] = *reinterpret_cast<const short8*>(&a_hi[so]);
      Al[m] = *reinterpret_cast<const short8*>(&a_lo[so]);
    }
    #pragma unroll
    for (int nt = 0; nt < 4; ++nt){
      const size_t bo = (((size_t)((q*4+nt)*8 + ks)*64 + lane) << 3);
      const short8 Bh = *reinterpret_cast<const short8*>(bth + bo);
      const short8 Bl = *reinterpret_cast<const short8*>(btl + bo);
      #pragma unroll
      for (int m = 0; m < 2; ++m){
        acc[m][nt] = __builtin_amdgcn_mfma_f32_16x16x32_bf16(Ah[m], Bh, acc[m][nt], 0,0,0);
        acc[m][nt] = __builtin_amdgcn_mfma_f32_16x16x32_bf16(Ah[m], Bl, acc[m][nt], 0,0,0);
        acc[m][nt] = __builtin_amdgcn_mfma_f32_16x16x32_bf16(Al[m], Bh, acc[m][nt], 0,0,0);
      }
    }
  }

  // ---- epilogue: bias + ReLU + W2 dot; reduce 16 n-lanes; combine 8 waves ----
  float w2v[4], b1v[4];
  #pragma unroll
  for (int nt=0; nt<4; ++nt){
    const int n = q*64 + nt*16 + mrow;    // C: col = lane&15
    w2v[nt] = W2[n]; b1v[nt] = b1[n];
  }
  #pragma unroll
  for (int mt=0; mt<2; ++mt){
    #pragma unroll
    for (int r=0; r<4; ++r){
      float s = 0.f;
      #pragma unroll
      for (int nt=0; nt<4; ++nt)
        s += fmaxf(acc[mt][nt][r] + b1v[nt], 0.f) * w2v[nt];
      s += __shfl_xor(s, 1, 64);
      s += __shfl_xor(s, 2, 64);
      s += __shfl_xor(s, 4, 64);
      s += __shfl_xor(s, 8, 64);
      if (mrow == 0)
        sred[q*32 + mt*16 + kgrp*4 + r] = s;   // C: row = (lane>>4)*4 + reg
    }
  }
  __syncthreads();
  if (tid < MROWS){
    const int rr = brow + tid;
    float tot = b2[0];
    #pragma unroll
    for (int w = 0; w < 8; ++w) tot += sred[w*32 + tid];
    const float m = 1.f / (1.f + expf(-tot));
    mask_out[rr] = m;
    atomicAdd(&cnt_all[s2g[rr]], 1);
    if (fabsf(m - 0.4f) < RMARG || fabsf(m - 0.3f) < RMARG){
      const int p = atomicAdd(rcnt, 1);
      if (p < RCAP) rlist[p] = rr;
    }
  }
}

// ---------------- refine: exact fp32 logit, MLP-parallel ----------------
__global__ __launch_bounds__(512) void refine_kernel(
    const float* __restrict__ hsub, const float* __restrict__ W1,
    const float* __restrict__ b1, const float* __restrict__ W2,
    const float* __restrict__ b2, const int* __restrict__ rlist,
    const int* __restrict__ rcnt, float* __restrict__ mask_out)
{
  __shared__ float arow[256];
  __shared__ float red[512];
  const int n = min(rcnt[0], RCAP);
  const int t = threadIdx.x;            // j = t, 0..511
  for (int it = blockIdx.x; it < n; it += gridDim.x){
    const int row = rlist[it];
    if (t < 256) arow[t] = hsub[(size_t)row*DIM + t];
    __syncthreads();
    float y0 = b1[t], y1 = 0.f, y2 = 0.f, y3 = 0.f;
    #pragma unroll 8
    for (int k = 0; k < 64; ++k){
      y0 = fmaf(arow[k],     W1[(size_t)k*512 + t],         y0);
      y1 = fmaf(arow[k+64],  W1[(size_t)(k+64)*512 + t],    y1);
      y2 = fmaf(arow[k+128], W1[(size_t)(k+128)*512 + t],   y2);
      y3 = fmaf(arow[k+192], W1[(size_t)(k+192)*512 + t],   y3);
    }
    const float y = (y0 + y1) + (y2 + y3);
    red[t] = fmaxf(y, 0.f) * W2[t];
    __syncthreads();
    #pragma unroll
    for (int off = 256; off > 0; off >>= 1){
      if (t < off) red[t] += red[t+off];
      __syncthreads();
    }
    if (t == 0) mask_out[row] = 1.f / (1.f + expf(-(red[0] + b2[0])));
    __syncthreads();
  }
}

// ---------------- CSR build: scan + fill ----------------
__global__ __launch_bounds__(1024) void scan_kernel(const int* __restrict__ cnt,
                                                    int* __restrict__ offs,
                                                    int* __restrict__ cursor){
  __shared__ int buf[1024];
  const int t = threadIdx.x;
  const int c0 = cnt[t*4], c1 = cnt[t*4+1], c2 = cnt[t*4+2], c3 = cnt[t*4+3];
  const int s = c0+c1+c2+c3;
  buf[t] = s; __syncthreads();
  for (int d = 1; d < 1024; d <<= 1){
    int v = (t >= d) ? buf[t-d] : 0;
    __syncthreads();
    buf[t] += v;
    __syncthreads();
  }
  const int excl = buf[t] - s;
  const int o0 = excl, o1 = excl+c0, o2 = o1+c1, o3 = o2+c2;
  offs[t*4]=o0; offs[t*4+1]=o1; offs[t*4+2]=o2; offs[t*4+3]=o3;
  cursor[t*4]=o0; cursor[t*4+1]=o1; cursor[t*4+2]=o2; cursor[t*4+3]=o3;
  if (t == 1023) offs[4096] = buf[1023];
}

__global__ void fill_kernel(const int* __restrict__ s2g, int* __restrict__ cursor,
                            int* __restrict__ list){
  const int i = blockIdx.x*blockDim.x + threadIdx.x;
  if (i < N_SUB){
    const int g = s2g[i];
    const int p = atomicAdd(&cursor[g], 1);
    list[p] = i;
  }
}

// ---------------- kernel C: per-graph masked means (replica-spread atomics) ----------------
__global__ __launch_bounds__(256) void graph_means(
    const float* __restrict__ hsub, const float* __restrict__ mask,
    const int* __restrict__ list, const int* __restrict__ offs,
    const float* __restrict__ hgraph, const float* __restrict__ Wc,
    const float* __restrict__ bc, unsigned short* __restrict__ hatAb,
    float* __restrict__ S32, float* __restrict__ Se32,
    int* __restrict__ nzflags, int* __restrict__ counters,
    float* __restrict__ out)
{
  __shared__ int   sidx[256];
  __shared__ unsigned char sflag[256];
  __shared__ float wr4[4][4];
  __shared__ float wrc[TCLS][4];
  const int g = blockIdx.x;
  const int t = threadIdx.x;
  const int w = t >> 6, lane = t & 63;
  const int start = offs[g], end = offs[g+1];
  const int cnt = end - start;
  float sv = 0.f, sev = 0.f;
  int cv = 0, ce = 0;
  for (int base = 0; base < cnt; base += 256){
    const int nb = min(256, cnt - base);
    __syncthreads();
    if (t < nb){
      const int i = list[start + base + t];
      sidx[t] = i;
      const float m = mask[i];
      sflag[t] = (m > 0.4f) ? 1 : ((m <= 0.3f) ? 2 : 0);
    }
    __syncthreads();
    for (int p = 0; p < nb; p += 4){
      const int lim = nb - p;
      const int i0 = sidx[p];
      const int i1 = (lim > 1) ? sidx[p+1] : i0;
      const int i2 = (lim > 2) ? sidx[p+2] : i0;
      const int i3 = (lim > 3) ? sidx[p+3] : i0;
      const int f0 = sflag[p];
      const int f1 = (lim > 1) ? sflag[p+1] : 0;
      const int f2 = (lim > 2) ? sflag[p+2] : 0;
      const int f3 = (lim > 3) ? sflag[p+3] : 0;
      const float v0 = hsub[(size_t)i0*DIM + t];
      const float v1 = hsub[(size_t)i1*DIM + t];
      const float v2 = hsub[(size_t)i2*DIM + t];
      const float v3 = hsub[(size_t)i3*DIM + t];
      if (f0==1){ sv+=v0; cv++; } else if (f0==2){ sev+=v0; ce++; }
      if (f1==1){ sv+=v1; cv++; } else if (f1==2){ sev+=v1; ce++; }
      if (f2==1){ sv+=v2; cv++; } else if (f2==2){ sev+=v2; ce++; }
      if (f3==1){ sv+=v3; cv++; } else if (f3==2){ sev+=v3; ce++; }
    }
  }
  __syncthreads();
  const float aligned = sv  / fmaxf((float)cv, 1.f);
  const float envv    = sev / fmaxf((float)ce, 1.f);
  float r0 = wave_reduce(aligned*aligned);
  float r1 = wave_reduce(envv*envv);
  float r2 = wave_reduce(aligned != 0.f ? 1.f : 0.f);
  float r3 = wave_reduce(envv    != 0.f ? 1.f : 0.f);
  if (lane == 0){ wr4[w][0]=r0; wr4[w][1]=r1; wr4[w][2]=r2; wr4[w][3]=r3; }
  __syncthreads();
  const float an2  = wr4[0][0]+wr4[1][0]+wr4[2][0]+wr4[3][0];
  const float en2  = wr4[0][1]+wr4[1][1]+wr4[2][1]+wr4[3][1];
  const float nzpf = wr4[0][2]+wr4[1][2]+wr4[2][2]+wr4[3][2];
  const float nzef = wr4[0][3]+wr4[1][3]+wr4[2][3]+wr4[3][3];
  const bool nzp = nzpf > 0.f, nze = nzef > 0.f;
  const float an = fmaxf(sqrtf(an2), 1e-8f);
  const float en = fmaxf(sqrtf(en2), 1e-8f);
  const float ha = aligned / an;
  hatAb[(size_t)g*DIM + t] = (unsigned short)bf16_rne(ha);
  atomicAdd(&S32[((g & (NREP-1)) << 8) + t], ha);
  if (nze) atomicAdd(&Se32[((g & (NREP-1)) << 8) + t], envv / en);
  if (t == 0){
    nzflags[g] = nzp ? 1 : 0;
    if (nzp) atomicAdd(&counters[0], 1);
    if (nze) atomicAdd(&counters[1], 1);
  }
  const float hg = hgraph[(size_t)g*DIM + t];
  #pragma unroll
  for (int c = 0; c < TCLS; ++c){
    float part = hg*Wc[t*TCLS+c] + aligned*Wc[(DIM+t)*TCLS+c];
    part = wave_reduce(part);
    if (lane == 0) wrc[c][w] = part;
  }
  __syncthreads();
  if (t < TCLS)
    out[g*TCLS + t] = wrc[t][0]+wrc[t][1]+wrc[t][2]+wrc[t][3] + bc[t];
}

// ---------------- combine: fold S/Se replicas (16 blocks x 2 reps + atomic merge) ----------------
__global__ __launch_bounds__(256) void combine_kernel(const float* __restrict__ S32,
                                                      const float* __restrict__ Se32,
                                                      float* __restrict__ S,
                                                      float* __restrict__ Se){
  const int b = blockIdx.x;       // 0..15
  const int t = threadIdx.x;
  float s = 0.f, se = 0.f;
  #pragma unroll
  for (int r = 0; r < 2; ++r){
    s  += S32[(b*2 + r)*DIM + t];
    se += Se32[(b*2 + r)*DIM + t];
  }
  atomicAdd(&S[t], s);
  atomicAdd(&Se[t], se);
}

// ---------------- kernel D: contrastive loss via rank-1 identity ----------------
__global__ __launch_bounds__(256) void loss_kernel(
    const unsigned short* __restrict__ hatAb, const float* __restrict__ S,
    const float* __restrict__ Se, const int* __restrict__ nzflags,
    const int* __restrict__ counters, float* __restrict__ loss_p)
{
  __shared__ float wr[4][2];
  const int g = blockIdx.x, t = threadIdx.x;
  const int w = t >> 6, lane = t & 63;
  const float ha = bf16_to_f((short)hatAb[(size_t)g*DIM + t]);
  float p0 = wave_reduce(ha*S[t]);
  float p1 = wave_reduce(ha*Se[t]);
  if (lane == 0){ wr[w][0] = p0; wr[w][1] = p1; }
  __syncthreads();
  if (t == 0){
    const float dS  = wr[0][0]+wr[1][0]+wr[2][0]+wr[3][0];
    const float dSe = wr[0][1]+wr[1][1]+wr[2][1]+wr[3][1];
    const int nzp_cnt = counters[0];
    const int nenv = counters[1];
    const float pos_num = fmaxf((float)(nzp_cnt - 1), 1.f);
    const float positive = (4096.f - dS) / pos_num;
    const float negative = ((float)nenv - dSe) / fmaxf((float)nenv, 1.f);
    float contrib = fmaxf(positive - negative + 1.f, 0.f);
    contrib *= (nzflags[g] ? 1.f : 0.f) * ((nenv > 0) ? 1.f : 0.f);
    atomicAdd(&loss_p[g & 63], contrib * (1.f/4096.f));
  }
}

// ---------------- final: fold loss partials ----------------
__global__ void final_loss(const float* __restrict__ loss_p, float* __restrict__ loss){
  const int t = threadIdx.x;    // 64 threads
  float v = loss_p[t];
  v = wave_reduce(v);
  if (t == 0) loss[0] = v;
}

// ---------------- launch ----------------
extern "C" void kernel_launch(void* const* d_in, const int* in_sizes, int n_in,
                              void* d_out, int out_size, void* d_ws, size_t ws_size,
                              hipStream_t stream) {
  const float* h_graph = (const float*)d_in[0];
  const float* h_sub   = (const float*)d_in[1];
  const float* W1      = (const float*)d_in[2];
  const float* b1      = (const float*)d_in[3];
  const float* W2      = (const float*)d_in[4];
  const float* b2      = (const float*)d_in[5];
  const float* Wc      = (const float*)d_in[6];
  const float* bc      = (const float*)d_in[7];
  const int*   s2g     = (const int*)d_in[8];

  float* out  = (float*)d_out;          // [4096,10]
  float* loss = out + N_GR*TCLS;        // scalar
  float* mask = loss + 1;               // [200000]

  // workspace layout — ~3.6 MB (proven-safe envelope 5.06 MB)
  char* ws = (char*)d_ws;
  short* bth    = (short*)ws;                          // 256 KB
  short* btl    = bth + HID*DIM;                       // 256 KB
  unsigned short* hatAb = (unsigned short*)(btl + HID*DIM);  // 2 MB
  int* cnt_all  = (int*)(hatAb + (size_t)N_GR*DIM);    // 4096
  int* offs     = cnt_all + N_GR;                      // 4097
  int* cursor   = offs + N_GR + 1;                     // 4096
  int* list     = cursor + N_GR;                       // 200000
  int* nzflags  = list + N_SUB;                        // 4096
  int* counters = nzflags + N_GR;                      // 2
  int* rcnt     = counters + 2;                        // 1
  int* rlist    = rcnt + 1;                            // 16384
  float* S      = (float*)(rlist + RCAP);              // 256
  float* Se     = S + DIM;                             // 256
  float* S32    = Se + DIM;                            // 32*256 (32 KB)
  float* Se32   = S32 + NREP*DIM;                      // 32*256 (32 KB)
  float* loss_p = Se32 + NREP*DIM;                     // 64

  hipLaunchKernelGGL(bconv_kernel, dim3(HID*DIM/256), dim3(256), 0, stream,
                     W1, bth, btl, cnt_all, S32, Se32, S, Se, counters, loss_p, rcnt);
  hipLaunchKernelGGL(mask_gemm, dim3(N_SUB/MROWS), dim3(512), 0, stream,
                     h_sub, bth, btl, b1, W2, b2, s2g, mask, cnt_all, rlist, rcnt);
  hipLaunchKernelGGL(refine_kernel, dim3(384), dim3(512), 0, stream,
                     h_sub, W1, b1, W2, b2, rlist, rcnt, mask);
  hipLaunchKernelGGL(scan_kernel, dim3(1), dim3(1024), 0, stream,
                     cnt_all, offs, cursor);
  hipLaunchKernelGGL(fill_kernel, dim3((N_SUB+255)/256), dim3(256), 0, stream,
                     s2g, cursor, list);
  hipLaunchKernelGGL(graph_means, dim3(N_GR), dim3(256), 0, stream,
                     h_sub, mask, list, offs, h_graph, Wc, bc,
                     hatAb, S32, Se32, nzflags, counters, out);
  hipLaunchKernelGGL(combine_kernel, dim3(16), dim3(256), 0, stream,
                     S32, Se32, S, Se);
  hipLaunchKernelGGL(loss_kernel, dim3(N_GR), dim3(256), 0, stream,
                     hatAb, S, Se, nzflags, counters, loss_p);
  hipLaunchKernelGGL(final_loss, dim3(1), dim3(64), 0, stream,
                     loss_p, loss);
}